// Round 8
// baseline (147.183 us; speedup 1.0000x reference)
//
#include <hip/hip_runtime.h>
#include <hip/hip_fp16.h>

#define N_TOK 16384
#define D 64
#define NC 512
#define KSEL 16
#define NPAIR (N_TOK * KSEL)   // 262144 real (token,rank) pairs
#define PADCAP 327168          // 262144 + 512*127: per-center segments padded to 128

typedef __attribute__((ext_vector_type(8))) short short8;
typedef __attribute__((ext_vector_type(8))) unsigned short ushort8;
typedef __attribute__((ext_vector_type(16))) float float16;

__device__ __forceinline__ unsigned fkey(float f) {
    unsigned u = __float_as_uint(f);
    return (u & 0x80000000u) ? ~u : (u | 0x80000000u);
}
__device__ __forceinline__ float funkey(unsigned k) {
    unsigned u = (k & 0x80000000u) ? (k & 0x7fffffffu) : ~k;
    return __uint_as_float(u);
}
__device__ __forceinline__ unsigned short bfr(float f) {  // fp32 -> bf16 RNE
    unsigned u = __float_as_uint(f);
    return (unsigned short)((u + 0x7FFFu + ((u >> 16) & 1u)) >> 16);
}
__device__ __forceinline__ float b2f(unsigned short h) {  // bf16 -> fp32
    return __uint_as_float((unsigned)h << 16);
}

__device__ __forceinline__ void ins16(unsigned (&run)[16], unsigned k) {
    #pragma unroll
    for (int r = 0; r < 16; ++r) {
        unsigned mx = run[r] > k ? run[r] : k;
        unsigned mn = run[r] > k ? k : run[r];
        run[r] = mx; k = mn;
    }
}

// ---------------- kernel Z: prep (splits + Wv transpose + table inits) -------
__global__ __launch_bounds__(256) void prep2_kernel(
    const float* __restrict__ x, const float* __restrict__ ctrs,
    const float* __restrict__ Wv,
    unsigned short* __restrict__ xh, unsigned short* __restrict__ xl,
    unsigned short* __restrict__ cbf, float* __restrict__ c2g,
    unsigned short* __restrict__ wbt, int* __restrict__ tokentab,
    int* __restrict__ hist) {
    __shared__ unsigned short tw[64 * 68];
    const int b = blockIdx.x, t = threadIdx.x;
    if (b < 512) {            // x rows: thread splits 8 dims
        int g = b * 256 + t;
        int row = g >> 3, seg = g & 7;
        const float4* xp = (const float4*)(x + row * 64 + seg * 8);
        float4 u = xp[0], v = xp[1];
        float c[8] = {u.x, u.y, u.z, u.w, v.x, v.y, v.z, v.w};
        ushort8 h, l;
        #pragma unroll
        for (int j = 0; j < 8; ++j) {
            h[j] = bfr(c[j]);
            l[j] = bfr(c[j] - b2f(h[j]));
        }
        *(ushort8*)(xh + row * 64 + seg * 8) = h;
        *(ushort8*)(xl + row * 64 + seg * 8) = l;
    } else if (b < 516) {     // ctrs: 2 threads per center (q = 32-dim half)
        int g = (b - 512) * 256 + t;   // 0..1023
        int c = g >> 1, q = g & 1;
        const float4* cp = (const float4*)(ctrs + c * D + q * 32);
        unsigned short* Ch = cbf + c * 136 + q * 32;
        float s2 = 0.f;
        #pragma unroll
        for (int i = 0; i < 8; ++i) {
            float4 v = cp[i];
            s2 += v.x * v.x + v.y * v.y + v.z * v.z + v.w * v.w;
            unsigned short h0 = bfr(v.x), h1 = bfr(v.y), h2 = bfr(v.z), h3 = bfr(v.w);
            unsigned short l0 = bfr(v.x - b2f(h0)), l1 = bfr(v.y - b2f(h1));
            unsigned short l2 = bfr(v.z - b2f(h2)), l3 = bfr(v.w - b2f(h3));
            *(uint2*)(Ch + 4 * i) =
                make_uint2((unsigned)h0 | ((unsigned)h1 << 16),
                           (unsigned)h2 | ((unsigned)h3 << 16));
            *(uint2*)(Ch + 64 + 4 * i) =
                make_uint2((unsigned)l0 | ((unsigned)l1 << 16),
                           (unsigned)l2 | ((unsigned)l3 << 16));
        }
        s2 += __shfl_xor(s2, 1);
        c2g[c] = s2;          // both q-threads write same value: benign
    } else if (b < 1028) {    // Wv transpose via LDS: Wbt[c][p][g] = W[c][g][p]
        const float* Wp = Wv + (size_t)(b - 516) * 4096;
        #pragma unroll
        for (int i = 0; i < 16; ++i) {
            int e = t + 256 * i;           // e = g*64 + p
            tw[(e & 63) * 68 + (e >> 6)] = bfr(Wp[e]);
        }
        __syncthreads();
        unsigned short* Wo = wbt + (size_t)(b - 516) * 4096;
        #pragma unroll
        for (int i = 0; i < 2; ++i) {
            int idx8 = t + 256 * i;        // ushort8 index
            int p = idx8 >> 3, g0 = (idx8 & 7) * 8;
            ushort8 v;
            #pragma unroll
            for (int j = 0; j < 8; ++j) v[j] = tw[p * 68 + g0 + j];
            *(ushort8*)(Wo + idx8 * 8) = v;
        }
    } else if (b < 1348) {    // tokentab -1 fill (81792 int4)
        int i = (b - 1028) * 256 + t;
        if (i < PADCAP / 4) ((int4*)tokentab)[i] = make_int4(-1, -1, -1, -1);
    } else {                  // hist[512] + cursor[512] zero (adjacent)
        hist[t] = 0; hist[t + 256] = 0; hist[t + 512] = 0; hist[t + 768] = 0;
    }
}

// ---------------- kernel B: fused dist + full top-16 + softmax + hist --------
// Replaces topk15 + topmerge (+ the 8MB pk round-trip). Block = 32 tokens x
// all 512 ctrs in 4 phases of 128. Register-prefetched Cbf copy overlaps the
// previous phase's selection; run[16] persists in regs across phases (64 keys/
// thread total -- same VALU as topk15+merge). Final 8-way tournament merge,
// softmax, scores/sidx/hist emitted directly (topmerge's verified code).
// Sbk columns XOR-swizzled by (row>>3) to break the 8-way select-read bank
// conflict (write and read sides apply the same involution).
__global__ __launch_bounds__(256, 2) void topk16_kernel(
    const unsigned short* __restrict__ xh, const unsigned short* __restrict__ xl,
    const unsigned short* __restrict__ cbf, const float* __restrict__ c2g,
    float* __restrict__ scores, int* __restrict__ sidx, int* __restrict__ hist) {
    __shared__ __align__(16) unsigned char pool[53760];
    unsigned short* Cbf = (unsigned short*)pool;      // [128 ctr][136]
    unsigned* Sbk = (unsigned*)(pool + 34816);        // [32 tok][132] keys / mbp
    float* c2s = (float*)(pool + 51712);              // [512]
    int* lhist = (int*)pool;                          // overlay on Cbf (final)

    const int t = threadIdx.x;
    const int lane = t & 63;
    const int wv = t >> 6;
    const int mrow = lane & 31;
    const int half = lane >> 5;
    const int base = blockIdx.x * 32;

    // A frags: token = base + mrow (identical across waves; L2-cheap)
    short8 ah[4], al[4];
    {
        const unsigned short* xph = xh + (size_t)(base + mrow) * 64 + half * 8;
        const unsigned short* xpl = xl + (size_t)(base + mrow) * 64 + half * 8;
        #pragma unroll
        for (int kt = 0; kt < 4; ++kt) {
            ah[kt] = *(const short8*)(xph + kt * 16);
            al[kt] = *(const short8*)(xpl + kt * 16);
        }
    }

    // preload phase-0 Cbf panel (2176 uint4)
    const uint4* csrc = (const uint4*)cbf;
    uint4 pre[8], pre8;
    #pragma unroll
    for (int i = 0; i < 8; ++i) pre[i] = csrc[t + 256 * i];
    if (t < 128) pre8 = csrc[2048 + t];

    unsigned run[16];
    #pragma unroll
    for (int r = 0; r < 16; ++r) run[r] = 0u;

    const int tok = t & 31;
    const int part = t >> 5;           // 0..7: 16-ctr slice per phase

    #pragma unroll 1
    for (int p = 0; p < 4; ++p) {
        // store staged panel (prev MFMA reads + prev select done at loop-end barrier)
        {
            uint4* dst = (uint4*)pool;
            #pragma unroll
            for (int i = 0; i < 8; ++i) dst[t + 256 * i] = pre[i];
            if (t < 128) dst[2048 + t] = pre8;
        }
        if (p == 0) { c2s[t] = c2g[t]; c2s[t + 256] = c2g[t + 256]; }
        if (p < 3) {                   // prefetch next panel
            const uint4* s2 = csrc + (p + 1) * 2176;
            #pragma unroll
            for (int i = 0; i < 8; ++i) pre[i] = s2[t + 256 * i];
            if (t < 128) pre8 = s2[2048 + t];
        }
        __syncthreads();   // (1) Cbf ready; Sbk writable (prev select done)

        // MFMA: wave's 32-ctr group, bf16 hi/lo split (3 terms x 4 kt)
        float16 acc = {0.f,0.f,0.f,0.f,0.f,0.f,0.f,0.f,0.f,0.f,0.f,0.f,0.f,0.f,0.f,0.f};
        const unsigned short* B0 = Cbf + (wv * 32 + mrow) * 136 + half * 8;
        #pragma unroll
        for (int kt = 0; kt < 4; ++kt) {
            short8 bh = *(const short8*)(B0 + kt * 16);
            short8 bl = *(const short8*)(B0 + 64 + kt * 16);
            acc = __builtin_amdgcn_mfma_f32_32x32x16_bf16(ah[kt], bh, acc, 0, 0, 0);
            acc = __builtin_amdgcn_mfma_f32_32x32x16_bf16(al[kt], bh, acc, 0, 0, 0);
            acc = __builtin_amdgcn_mfma_f32_32x32x16_bf16(ah[kt], bl, acc, 0, 0, 0);
        }

        // keygen: thread owns ctr col (wv*32+mrow), 16 token rows
        {
            const int cglob = p * 128 + wv * 32 + mrow;
            const int col = wv * 32 + mrow;
            const float cc = c2s[cglob];
            #pragma unroll
            for (int reg = 0; reg < 16; ++reg) {
                int tokrow = (reg & 3) + 8 * (reg >> 2) + 4 * half;
                float sq = fmaf(2.f, acc[reg], -cc);
                int colw = col ^ (((tokrow >> 3) & 3) << 2);   // bank swizzle
                Sbk[tokrow * 132 + colw] =
                    (fkey(sq) & 0xFFFFFE00u) | (unsigned)cglob;
            }
        }
        __syncthreads();   // (2) keys ready

        // select: 16 keys of this thread's (tok, part) slice
        const int sw = ((tok >> 3) & 3) << 2;
        #pragma unroll
        for (int j = 0; j < 4; ++j) {
            int colb = (part * 16 + 4 * ((j + tok) & 3)) ^ sw;
            uint4 kv = *(const uint4*)(Sbk + tok * 132 + colb);
            ins16(run, kv.x); ins16(run, kv.y); ins16(run, kv.z); ins16(run, kv.w);
        }
        __syncthreads();   // (3) select done -> Cbf/Sbk writable next phase
    }

    // dump runs to mbp (Sbk region, plain layout) + zero lhist (Cbf region)
    {
        uint4* d = (uint4*)(Sbk + tok * 132 + part * 16);
        d[0] = make_uint4(run[0], run[1], run[2], run[3]);
        d[1] = make_uint4(run[4], run[5], run[6], run[7]);
        d[2] = make_uint4(run[8], run[9], run[10], run[11]);
        d[3] = make_uint4(run[12], run[13], run[14], run[15]);
    }
    lhist[t] = 0; lhist[t + 256] = 0;
    __syncthreads();   // (4)

    if (t < 32) {      // 8-way tournament merge (topmerge's verified loop)
        const unsigned* pm = Sbk + t * 132;
        unsigned h[8]; int pos[8];
        #pragma unroll
        for (int w = 0; w < 8; ++w) { pos[w] = 0; h[w] = pm[w * 16]; }
        float vals[16]; int ids[16];
        #pragma unroll
        for (int r = 0; r < KSEL; ++r) {
            unsigned m = h[0];
            #pragma unroll
            for (int w = 1; w < 8; ++w) m = m > h[w] ? m : h[w];
            vals[r] = funkey(m);
            ids[r] = (int)(m & 511u);
            #pragma unroll
            for (int w = 0; w < 8; ++w) {
                if (h[w] == m) {
                    ++pos[w];
                    h[w] = (pos[w] < KSEL) ? pm[w * 16 + pos[w]] : 0u;
                }
            }
        }
        float mx = vals[0];
        float e[16]; float sum = 0.f;
        #pragma unroll
        for (int r = 0; r < KSEL; ++r) { e[r] = __expf(vals[r] - mx); sum += e[r]; }
        float inv = 1.f / sum;
        int n = base + t;
        #pragma unroll
        for (int q = 0; q < 4; ++q) {
            *(float4*)(scores + n * KSEL + 4 * q) =
                make_float4(e[4*q] * inv, e[4*q+1] * inv, e[4*q+2] * inv, e[4*q+3] * inv);
            *(int4*)(sidx + n * KSEL + 4 * q) =
                make_int4(ids[4*q], ids[4*q+1], ids[4*q+2], ids[4*q+3]);
        }
        #pragma unroll
        for (int r = 0; r < KSEL; ++r) atomicAdd(&lhist[ids[r]], 1);
    }
    __syncthreads();   // (5)
    { int hv = lhist[t]; if (hv) atomicAdd(&hist[t], hv); }
    { int hv = lhist[t + 256]; if (hv) atomicAdd(&hist[t + 256], hv); }
}

// ---------------- kernel P: scatter with fused per-block prefix scan ---------
__global__ __launch_bounds__(256) void scatter5_kernel(
    const int* __restrict__ hist, const int* __restrict__ sidx,
    const float* __restrict__ scores, int* __restrict__ cursor,
    int* __restrict__ tokentab, float* __restrict__ scotab,
    int* __restrict__ meta) {
    __shared__ int buf[2][NC];
    __shared__ int sb[NC];
    __shared__ int lh[NC];
    __shared__ int lbase[NC];
    const int t = threadIdx.x;

    // padded inclusive scan of hist (9 rounds, 2 elems/thread)
    int h0 = hist[t], h1 = hist[t + 256];
    int p0 = (h0 + 127) & ~127, p1 = (h1 + 127) & ~127;
    buf[0][t] = p0; buf[0][t + 256] = p1;
    __syncthreads();
    int a = 0;
    for (int d = 1; d < NC; d <<= 1) {
        int v0 = buf[a][t] + (t >= d ? buf[a][t - d] : 0);
        int v1 = buf[a][t + 256] + (t + 256 >= d ? buf[a][t + 256 - d] : 0);
        buf[1 - a][t] = v0; buf[1 - a][t + 256] = v1;
        __syncthreads();
        a ^= 1;
    }
    sb[t] = buf[a][t] - p0;
    sb[t + 256] = buf[a][t + 256] - p1;
    if (t == 255) meta[0] = buf[a][NC - 1];   // total (same in every block)
    lh[t] = 0; lh[t + 256] = 0;
    __syncthreads();

    const int base_e = blockIdx.x * 1024;
    int myc[4];
    #pragma unroll
    for (int i = 0; i < 4; ++i) {
        int c = sidx[base_e + t + 256 * i];
        myc[i] = c;
        atomicAdd(&lh[c], 1);
    }
    __syncthreads();
    for (int i = t; i < NC; i += 256) {
        int h = lh[i];
        lbase[i] = h ? (sb[i] + atomicAdd(&cursor[i], h)) : 0;
        lh[i] = 0;
    }
    __syncthreads();
    #pragma unroll
    for (int i = 0; i < 4; ++i) {
        int e = base_e + t + 256 * i;
        int c = myc[i];
        int pos = lbase[c] + atomicAdd(&lh[c], 1);
        tokentab[pos] = (c << 19) | e;
        scotab[pos] = scores[e];
    }
}

// ---------------- kernel C (fast): MFMA mix, bf16 inputs pre-staged ----------
__global__ __launch_bounds__(256) void mix17_kernel(
    const unsigned short* __restrict__ xh, const unsigned short* __restrict__ wbt,
    const float* __restrict__ Ov, const int* __restrict__ tokentab,
    const float* __restrict__ scotab, const int* __restrict__ meta,
    __half* __restrict__ partial) {
    __shared__ __align__(16) unsigned short Wt[64 * 72];   // 9216 B
    __shared__ int eT[128];
    __shared__ float sT[128];

    const int t = threadIdx.x;
    const int base = blockIdx.x * 128;
    if (base >= meta[0]) return;               // block-uniform, before barriers

    const int c = (int)(((unsigned)tokentab[base]) >> 19);

    // stage Wt: pure copy from Wbt[c] (layout already [p][g])
    {
        const unsigned short* Wp = wbt + (size_t)c * 4096;
        const int p = t >> 2, qq = t & 3;
        *(ushort8*)(Wt + p * 72 + qq * 16) =
            *(const ushort8*)(Wp + p * 64 + qq * 16);
        *(ushort8*)(Wt + p * 72 + qq * 16 + 8) =
            *(const ushort8*)(Wp + p * 64 + qq * 16 + 8);
    }
    if (t < 128) {
        unsigned w = (unsigned)tokentab[base + t];
        eT[t] = (int)(w & 0x7FFFFu);           // pad -> 0x7FFFF (>= NPAIR)
        sT[t] = scotab[base + t];              // pad -> garbage: row-contained
    }
    __syncthreads();

    const int lane = t & 63;
    const int wv = t >> 6;
    const int mrow = lane & 31;
    const int half = lane >> 5;
    const int row = wv * 32 + mrow;

    const int mye = eT[row];
    const int myn = (mye < NPAIR) ? (mye >> 4) : 0;   // clamp pad gather

    const unsigned short* xp = xh + (size_t)myn * 64 + half * 8;
    short8 a[4];
    #pragma unroll
    for (int kt = 0; kt < 4; ++kt) a[kt] = *(const short8*)(xp + kt * 16);

    float16 acc0 = {0.f,0.f,0.f,0.f,0.f,0.f,0.f,0.f,0.f,0.f,0.f,0.f,0.f,0.f,0.f,0.f};
    float16 acc1 = {0.f,0.f,0.f,0.f,0.f,0.f,0.f,0.f,0.f,0.f,0.f,0.f,0.f,0.f,0.f,0.f};

    const unsigned short* B0 = Wt + mrow * 72;
    const unsigned short* B1 = Wt + (mrow + 32) * 72;
    #pragma unroll
    for (int kt = 0; kt < 4; ++kt) {
        short8 b0 = *(const short8*)(B0 + kt * 16 + half * 8);
        short8 b1 = *(const short8*)(B1 + kt * 16 + half * 8);
        acc0 = __builtin_amdgcn_mfma_f32_32x32x16_bf16(a[kt], b0, acc0, 0, 0, 0);
        acc1 = __builtin_amdgcn_mfma_f32_32x32x16_bf16(a[kt], b1, acc1, 0, 0, 0);
    }

    const float ov0 = Ov[c * D + mrow];
    const float ov1 = Ov[c * D + 32 + mrow];
    #pragma unroll
    for (int reg = 0; reg < 16; ++reg) {
        int orow = wv * 32 + (reg & 3) + 8 * (reg >> 2) + 4 * half;
        float s = sT[orow];
        int e = eT[orow];
        if (e < NPAIR) {                       // pad rows: no stores
            __half* dst = partial + (size_t)e * D;
            dst[mrow]      = __float2half(s * (acc0[reg] + ov0));
            dst[32 + mrow] = __float2half(s * (acc1[reg] + ov1));
        }
    }
}

// ---------------- kernel R: per-token reduce of 16 fp16 contributions --------
__global__ __launch_bounds__(256) void redu2_kernel(
    const __half* __restrict__ partial, float* __restrict__ out) {
    const int g = blockIdx.x * 256 + threadIdx.x;   // N_TOK*8 threads
    const int n = g >> 3;
    const int d8 = (g & 7) * 8;
    const __half* p = partial + (size_t)n * (KSEL * D) + d8;
    float s[8] = {0.f, 0.f, 0.f, 0.f, 0.f, 0.f, 0.f, 0.f};
    #pragma unroll
    for (int r = 0; r < KSEL; ++r) {
        ushort8 v = *(const ushort8*)(p + r * D);
        #pragma unroll
        for (int j = 0; j < 8; ++j)
            s[j] += __half2float(__ushort_as_half((unsigned short)v[j]));
    }
    float* o = out + n * D + d8;
    *(float4*)(o)     = make_float4(s[0], s[1], s[2], s[3]);
    *(float4*)(o + 4) = make_float4(s[4], s[5], s[6], s[7]);
}

// ---------------- kernel C (fallback): original atomic epilogue ---------------
__global__ __launch_bounds__(256) void mix14_kernel(
    const float* __restrict__ x, const float* __restrict__ Wv,
    const float* __restrict__ Ov, const int* __restrict__ tokentab,
    const float* __restrict__ scotab, const int* __restrict__ meta,
    float* __restrict__ out) {
    __shared__ __align__(16) unsigned short Wt[64 * 72];
    __shared__ int tT[128];
    __shared__ float sT[128];

    const int t = threadIdx.x;
    const int base = blockIdx.x * 128;
    if (base >= meta[0]) return;

    const int c = (int)(((unsigned)tokentab[base]) >> 19);

    {
        const float* Wp = Wv + c * (D * D) + (t & 63);
        const int gb = (t >> 6) * 16;
        #pragma unroll
        for (int g = 0; g < 16; g += 2) {
            float v0 = Wp[(gb + g) * 64];
            float v1 = Wp[(gb + g + 1) * 64];
            unsigned pkw = (unsigned)bfr(v0) | ((unsigned)bfr(v1) << 16);
            *(unsigned*)&Wt[(t & 63) * 72 + gb + g] = pkw;
        }
    }
    if (t < 128) {
        unsigned w = (unsigned)tokentab[base + t];
        tT[t] = (int)((w & 0x7FFFFu) >> 4);    // pad (memset 0) -> token 0
        sT[t] = scotab[base + t];
    }
    __syncthreads();

    const int lane = t & 63;
    const int wv = t >> 6;
    const int mrow = lane & 31;
    const int half = lane >> 5;
    const int row = wv * 32 + mrow;

    const int   myn = tT[row];
    const float mys = sT[row];

    const float* xp = x + myn * D + half * 8;
    float4 f[8];
    #pragma unroll
    for (int kt = 0; kt < 4; ++kt) {
        f[2 * kt]     = *(const float4*)(xp + kt * 16);
        f[2 * kt + 1] = *(const float4*)(xp + kt * 16 + 4);
    }
    short8 a[4];
    #pragma unroll
    for (int kt = 0; kt < 4; ++kt) {
        float4 u = f[2 * kt], v = f[2 * kt + 1];
        a[kt][0] = (short)bfr(u.x * mys); a[kt][1] = (short)bfr(u.y * mys);
        a[kt][2] = (short)bfr(u.z * mys); a[kt][3] = (short)bfr(u.w * mys);
        a[kt][4] = (short)bfr(v.x * mys); a[kt][5] = (short)bfr(v.y * mys);
        a[kt][6] = (short)bfr(v.z * mys); a[kt][7] = (short)bfr(v.w * mys);
    }

    float16 acc0 = {0.f,0.f,0.f,0.f,0.f,0.f,0.f,0.f,0.f,0.f,0.f,0.f,0.f,0.f,0.f,0.f};
    float16 acc1 = {0.f,0.f,0.f,0.f,0.f,0.f,0.f,0.f,0.f,0.f,0.f,0.f,0.f,0.f,0.f,0.f};

    const unsigned short* B0 = Wt + mrow * 72;
    const unsigned short* B1 = Wt + (mrow + 32) * 72;
    #pragma unroll
    for (int kt = 0; kt < 4; ++kt) {
        short8 b0 = *(const short8*)(B0 + kt * 16 + half * 8);
        short8 b1 = *(const short8*)(B1 + kt * 16 + half * 8);
        acc0 = __builtin_amdgcn_mfma_f32_32x32x16_bf16(a[kt], b0, acc0, 0, 0, 0);
        acc1 = __builtin_amdgcn_mfma_f32_32x32x16_bf16(a[kt], b1, acc1, 0, 0, 0);
    }

    const float ov0 = Ov[c * D + mrow];
    const float ov1 = Ov[c * D + 32 + mrow];
    #pragma unroll
    for (int reg = 0; reg < 16; ++reg) {
        int orow = wv * 32 + (reg & 3) + 8 * (reg >> 2) + 4 * half;
        float s = sT[orow];
        if (s != 0.f) {
            int n = tT[orow];
            unsafeAtomicAdd(out + n * D + mrow,      acc0[reg] + s * ov0);
            unsafeAtomicAdd(out + n * D + 32 + mrow, acc1[reg] + s * ov1);
        }
    }
}

extern "C" void kernel_launch(void* const* d_in, const int* in_sizes, int n_in,
                              void* d_out, int out_size, void* d_ws, size_t ws_size,
                              hipStream_t stream) {
    const float* x    = (const float*)d_in[0];
    const float* ctrs = (const float*)d_in[1];
    const float* Wv   = (const float*)d_in[2];
    const float* Ov   = (const float*)d_in[3];
    float* out = (float*)d_out;

    // workspace layout (int offsets)
    const size_t OFF_META = 0;                       // 512
    const size_t OFF_HIST = 512;                     // 512
    const size_t OFF_CUR  = 1024;                    // 512 (adjacent to hist)
    const size_t OFF_SCO  = 2560;                    // NPAIR
    const size_t OFF_SIDX = OFF_SCO + NPAIR;         // NPAIR
    const size_t OFF_TTAB = OFF_SIDX + NPAIR;        // PADCAP
    const size_t OFF_STAB = OFF_TTAB + PADCAP;       // PADCAP
    const size_t XH_INTS  = (size_t)N_TOK * 32;      // N_TOK*64 bf16
    const size_t CBF_INTS = (size_t)NC * 68;         // 512*136 bf16
    const size_t WBT_INTS = (size_t)NC * 2048;       // 512*4096 bf16
    const size_t O_XH   = OFF_STAB + PADCAP;
    const size_t O_XL   = O_XH + XH_INTS;
    const size_t O_CBF  = O_XL + XH_INTS;
    const size_t O_C2   = O_CBF + CBF_INTS;
    const size_t O_WBT  = O_C2 + 512;
    const size_t O_PART = O_WBT + WBT_INTS;
    const size_t PART_INTS = (size_t)NPAIR * 32;     // NPAIR*64 halves

    int*    meta     = (int*)d_ws + OFF_META;
    int*    hist     = (int*)d_ws + OFF_HIST;
    int*    cursor   = (int*)d_ws + OFF_CUR;
    float*  scores   = (float*)d_ws + OFF_SCO;
    int*    sidx     = (int*)d_ws + OFF_SIDX;
    int*    tokentab = (int*)d_ws + OFF_TTAB;
    float*  scotab   = (float*)d_ws + OFF_STAB;
    unsigned short* xh  = (unsigned short*)((int*)d_ws + O_XH);
    unsigned short* xl  = (unsigned short*)((int*)d_ws + O_XL);
    unsigned short* cbf = (unsigned short*)((int*)d_ws + O_CBF);
    float*  c2g      = (float*)((int*)d_ws + O_C2);
    unsigned short* wbt = (unsigned short*)((int*)d_ws + O_WBT);
    __half* partial  = (__half*)((int*)d_ws + O_PART);

    const size_t need = (O_PART + PART_INTS) * 4;
    const bool fast = ws_size >= need;

    // prep2 does all table inits (tokentab=-1, hist/cursor=0) + splits + Wbt
    hipLaunchKernelGGL(prep2_kernel, dim3(1349), dim3(256), 0, stream,
                       x, ctrs, Wv, xh, xl, cbf, c2g, wbt, tokentab, hist);
    if (!fast) {
        // fallback expects tokentab=0 pads, zeroed scotab and out
        hipMemsetAsync(out, 0, (size_t)N_TOK * D * sizeof(float), stream);
        hipMemsetAsync(scotab, 0, (size_t)PADCAP * sizeof(float), stream);
        hipMemsetAsync(tokentab, 0, (size_t)PADCAP * sizeof(int), stream);
    }
    hipLaunchKernelGGL(topk16_kernel, dim3(N_TOK / 32), dim3(256), 0, stream,
                       xh, xl, cbf, c2g, scores, sidx, hist);
    hipLaunchKernelGGL(scatter5_kernel, dim3(256), dim3(256), 0, stream,
                       hist, sidx, scores, cursor, tokentab, scotab, meta);
    if (fast) {
        hipLaunchKernelGGL(mix17_kernel, dim3(PADCAP / 128), dim3(256), 0, stream,
                           xh, wbt, Ov, tokentab, scotab, meta, partial);
        hipLaunchKernelGGL(redu2_kernel, dim3(N_TOK * 8 / 256), dim3(256), 0, stream,
                           partial, out);
    } else {
        hipLaunchKernelGGL(mix14_kernel, dim3(PADCAP / 128), dim3(256), 0, stream,
                           x, Wv, Ov, tokentab, scotab, meta, out);
    }
}

// Round 9
// 137.511 us; speedup vs baseline: 1.0703x; 1.0703x over previous
//
#include <hip/hip_runtime.h>
#include <hip/hip_fp16.h>

#define N_TOK 16384
#define D 64
#define NC 512
#define KSEL 16
#define NPAIR (N_TOK * KSEL)   // 262144 real (token,rank) pairs
#define PADCAP 327168          // 262144 + 512*127: per-center segments padded to 128

typedef __attribute__((ext_vector_type(8))) short short8;
typedef __attribute__((ext_vector_type(8))) unsigned short ushort8;
typedef __attribute__((ext_vector_type(16))) float float16;

__device__ __forceinline__ unsigned fkey(float f) {
    unsigned u = __float_as_uint(f);
    return (u & 0x80000000u) ? ~u : (u | 0x80000000u);
}
__device__ __forceinline__ float funkey(unsigned k) {
    unsigned u = (k & 0x80000000u) ? (k & 0x7fffffffu) : ~k;
    return __uint_as_float(u);
}
__device__ __forceinline__ unsigned short bfr(float f) {  // fp32 -> bf16 RNE
    unsigned u = __float_as_uint(f);
    return (unsigned short)((u + 0x7FFFu + ((u >> 16) & 1u)) >> 16);
}
__device__ __forceinline__ float b2f(unsigned short h) {  // bf16 -> fp32
    return __uint_as_float((unsigned)h << 16);
}

__device__ __forceinline__ void ins16(unsigned (&run)[16], unsigned k) {
    #pragma unroll
    for (int r = 0; r < 16; ++r) {
        unsigned mx = run[r] > k ? run[r] : k;
        unsigned mn = run[r] > k ? k : run[r];
        run[r] = mx; k = mn;
    }
}

// ---------------- kernel Z: prep (splits + Wv transpose + table inits) -------
__global__ __launch_bounds__(256) void prep2_kernel(
    const float* __restrict__ x, const float* __restrict__ ctrs,
    const float* __restrict__ Wv,
    unsigned short* __restrict__ xh, unsigned short* __restrict__ xl,
    unsigned short* __restrict__ cbf, float* __restrict__ c2g,
    unsigned short* __restrict__ wbt, int* __restrict__ tokentab,
    int* __restrict__ hist) {
    __shared__ unsigned short tw[64 * 68];
    const int b = blockIdx.x, t = threadIdx.x;
    if (b < 512) {            // x rows: thread splits 8 dims
        int g = b * 256 + t;
        int row = g >> 3, seg = g & 7;
        const float4* xp = (const float4*)(x + row * 64 + seg * 8);
        float4 u = xp[0], v = xp[1];
        float c[8] = {u.x, u.y, u.z, u.w, v.x, v.y, v.z, v.w};
        ushort8 h, l;
        #pragma unroll
        for (int j = 0; j < 8; ++j) {
            h[j] = bfr(c[j]);
            l[j] = bfr(c[j] - b2f(h[j]));
        }
        *(ushort8*)(xh + row * 64 + seg * 8) = h;
        *(ushort8*)(xl + row * 64 + seg * 8) = l;
    } else if (b < 516) {     // ctrs: 2 threads per center (q = 32-dim half)
        int g = (b - 512) * 256 + t;   // 0..1023
        int c = g >> 1, q = g & 1;
        const float4* cp = (const float4*)(ctrs + c * D + q * 32);
        unsigned short* Ch = cbf + c * 136 + q * 32;
        float s2 = 0.f;
        #pragma unroll
        for (int i = 0; i < 8; ++i) {
            float4 v = cp[i];
            s2 += v.x * v.x + v.y * v.y + v.z * v.z + v.w * v.w;
            unsigned short h0 = bfr(v.x), h1 = bfr(v.y), h2 = bfr(v.z), h3 = bfr(v.w);
            unsigned short l0 = bfr(v.x - b2f(h0)), l1 = bfr(v.y - b2f(h1));
            unsigned short l2 = bfr(v.z - b2f(h2)), l3 = bfr(v.w - b2f(h3));
            *(uint2*)(Ch + 4 * i) =
                make_uint2((unsigned)h0 | ((unsigned)h1 << 16),
                           (unsigned)h2 | ((unsigned)h3 << 16));
            *(uint2*)(Ch + 64 + 4 * i) =
                make_uint2((unsigned)l0 | ((unsigned)l1 << 16),
                           (unsigned)l2 | ((unsigned)l3 << 16));
        }
        s2 += __shfl_xor(s2, 1);
        c2g[c] = s2;          // both q-threads write same value: benign
    } else if (b < 1028) {    // Wv transpose via LDS: Wbt[c][p][g] = W[c][g][p]
        const float* Wp = Wv + (size_t)(b - 516) * 4096;
        #pragma unroll
        for (int i = 0; i < 16; ++i) {
            int e = t + 256 * i;           // e = g*64 + p
            tw[(e & 63) * 68 + (e >> 6)] = bfr(Wp[e]);
        }
        __syncthreads();
        unsigned short* Wo = wbt + (size_t)(b - 516) * 4096;
        #pragma unroll
        for (int i = 0; i < 2; ++i) {
            int idx8 = t + 256 * i;        // ushort8 index
            int p = idx8 >> 3, g0 = (idx8 & 7) * 8;
            ushort8 v;
            #pragma unroll
            for (int j = 0; j < 8; ++j) v[j] = tw[p * 68 + g0 + j];
            *(ushort8*)(Wo + idx8 * 8) = v;
        }
    } else if (b < 1348) {    // tokentab -1 fill (81792 int4)
        int i = (b - 1028) * 256 + t;
        if (i < PADCAP / 4) ((int4*)tokentab)[i] = make_int4(-1, -1, -1, -1);
    } else {                  // hist[512] + cursor[512] zero (adjacent)
        hist[t] = 0; hist[t + 256] = 0; hist[t + 512] = 0; hist[t + 768] = 0;
    }
}

// ---------------- kernel B: dist via bf16-split MFMA + per-phase top-16 ------
// R7-verified structure (4 blocks/CU, phase-split grid). topk16's phase fusion
// regressed 13us (2 blocks/CU barrier convoy) -- reverted. New: exact
// threshold guard on ins16 (k <= run[15] is a provable no-op).
__global__ __launch_bounds__(256, 4) void topk15_kernel(
    const unsigned short* __restrict__ xh, const unsigned short* __restrict__ xl,
    const unsigned short* __restrict__ cbf, const float* __restrict__ c2g,
    unsigned* __restrict__ pk) {
    __shared__ __align__(16) unsigned char pool[35328];
    unsigned short* Cbf = (unsigned short*)pool;   // [128 ctr][136]: 0..63 ch, 64..127 cl
    unsigned* Sbk = (unsigned*)pool;               // overlay [64 tok][132] keys
    unsigned* mbp = (unsigned*)pool;               // overlay [64 tok][68]
    float* c2s = (float*)(pool + 34816);           // [128] ||c||^2

    const int t = threadIdx.x;
    const int lane = t & 63;
    const int wv = t >> 6;               // wave 0..3
    const int mrow = lane & 31;
    const int half = lane >> 5;
    const int tb = blockIdx.x >> 2;
    const int p = blockIdx.x & 3;
    const int base = tb * 64;
    const int cbase = p * 128;
    const int trow = (wv & 1) * 32;      // token-row group of this wave
    const int cgrp = (wv >> 1) * 64;     // ctr-col group base of this wave

    // ---- stage C: pure copy, 34816 B = 2176 uint4 ----
    {
        const uint4* src = (const uint4*)(cbf + (size_t)cbase * 136);
        uint4* dst = (uint4*)pool;
        #pragma unroll
        for (int i = 0; i < 8; ++i) dst[t + 256 * i] = src[t + 256 * i];
        if (t < 128) {
            dst[2048 + t] = src[2048 + t];
            c2s[t] = c2g[cbase + t];
        }
    }

    // ---- A frags: direct bf16 loads ----
    short8 ah[4], al[4];
    {
        const int xrow = base + trow + mrow;
        const unsigned short* xph = xh + (size_t)xrow * 64 + half * 8;
        const unsigned short* xpl = xl + (size_t)xrow * 64 + half * 8;
        #pragma unroll
        for (int kt = 0; kt < 4; ++kt) {
            ah[kt] = *(const short8*)(xph + kt * 16);
            al[kt] = *(const short8*)(xpl + kt * 16);
        }
    }
    __syncthreads();   // (1) Cbf/c2s staged

    float16 acc0 = {0.f,0.f,0.f,0.f,0.f,0.f,0.f,0.f,0.f,0.f,0.f,0.f,0.f,0.f,0.f,0.f};
    float16 acc1 = acc0;

    const unsigned short* B0 = Cbf + (cgrp + mrow) * 136 + half * 8;
    const unsigned short* B1 = Cbf + (cgrp + 32 + mrow) * 136 + half * 8;
    #pragma unroll
    for (int kt = 0; kt < 4; ++kt) {
        short8 bh0 = *(const short8*)(B0 + kt * 16);
        short8 bh1 = *(const short8*)(B1 + kt * 16);
        short8 bl0 = *(const short8*)(B0 + 64 + kt * 16);
        short8 bl1 = *(const short8*)(B1 + 64 + kt * 16);
        acc0 = __builtin_amdgcn_mfma_f32_32x32x16_bf16(ah[kt], bh0, acc0, 0, 0, 0);
        acc1 = __builtin_amdgcn_mfma_f32_32x32x16_bf16(ah[kt], bh1, acc1, 0, 0, 0);
        acc0 = __builtin_amdgcn_mfma_f32_32x32x16_bf16(al[kt], bh0, acc0, 0, 0, 0);
        acc1 = __builtin_amdgcn_mfma_f32_32x32x16_bf16(al[kt], bh1, acc1, 0, 0, 0);
        acc0 = __builtin_amdgcn_mfma_f32_32x32x16_bf16(ah[kt], bl0, acc0, 0, 0, 0);
        acc1 = __builtin_amdgcn_mfma_f32_32x32x16_bf16(ah[kt], bl1, acc1, 0, 0, 0);
    }
    __syncthreads();   // (2) Cbf reads done -> Sbk overlay safe

    // ---- keygen: all 128 ctr keys per token staged at once ----
    {
        float ca = c2s[cgrp + mrow];
        float cb = c2s[cgrp + 32 + mrow];
        #pragma unroll
        for (int reg = 0; reg < 16; ++reg) {
            int tokrow = trow + (reg & 3) + 8 * (reg >> 2) + 4 * half;
            float sa = fmaf(2.f, acc0[reg], -ca);
            float sb = fmaf(2.f, acc1[reg], -cb);
            Sbk[tokrow * 132 + cgrp + mrow] =
                (fkey(sa) & 0xFFFFFE00u) | (unsigned)(cbase + cgrp + mrow);
            Sbk[tokrow * 132 + cgrp + 32 + mrow] =
                (fkey(sb) & 0xFFFFFE00u) | (unsigned)(cbase + cgrp + 32 + mrow);
        }
    }
    __syncthreads();   // (3) keys staged

    // ---- selection: thread t -> token t&63, ctr-quarter t>>6 (32 keys) ----
    const int tok = t & 63;
    const int h = t >> 6;
    unsigned run[16];
    #pragma unroll
    for (int r = 0; r < 16; ++r) run[r] = 0u;
    #pragma unroll
    for (int i = 0; i < 8; ++i) {
        int cq = ((i + tok) & 7) ^ ((tok >> 3) & 7);   // bank-spread rotation
        uint4 kv = *(const uint4*)(Sbk + tok * 132 + 32 * h + 4 * cq);
        if (kv.x > run[15]) ins16(run, kv.x);
        if (kv.y > run[15]) ins16(run, kv.y);
        if (kv.z > run[15]) ins16(run, kv.z);
        if (kv.w > run[15]) ins16(run, kv.w);
    }
    __syncthreads();   // (4) Sbk dead -> mbp overlay safe

    {
        uint4* dst = (uint4*)(mbp + tok * 68 + h * 16);
        dst[0] = make_uint4(run[0], run[1], run[2], run[3]);
        dst[1] = make_uint4(run[4], run[5], run[6], run[7]);
        dst[2] = make_uint4(run[8], run[9], run[10], run[11]);
        dst[3] = make_uint4(run[12], run[13], run[14], run[15]);
    }
    __syncthreads();   // (5)

    if (t < 64) {      // 4-way tournament merge -> phase top-16, write pk
        const unsigned* pm = mbp + t * 68;
        unsigned hv[4]; int pos[4];
        #pragma unroll
        for (int w = 0; w < 4; ++w) { pos[w] = 0; hv[w] = pm[w * 16]; }
        unsigned mm[16];
        #pragma unroll
        for (int r = 0; r < 16; ++r) {
            unsigned m = hv[0];
            #pragma unroll
            for (int w = 1; w < 4; ++w) m = m > hv[w] ? m : hv[w];
            mm[r] = m;
            #pragma unroll
            for (int w = 0; w < 4; ++w) {
                if (hv[w] == m) {
                    ++pos[w];
                    hv[w] = (pos[w] < 16) ? pm[w * 16 + pos[w]] : 0u;
                }
            }
        }
        uint4* dst = (uint4*)(pk + (size_t)(base + t) * 64 + p * 16);
        dst[0] = make_uint4(mm[0], mm[1], mm[2], mm[3]);
        dst[1] = make_uint4(mm[4], mm[5], mm[6], mm[7]);
        dst[2] = make_uint4(mm[8], mm[9], mm[10], mm[11]);
        dst[3] = make_uint4(mm[12], mm[13], mm[14], mm[15]);
    }
}

// ---------------- kernel M: 4-way cross-phase merge + softmax + hist ---------
__global__ __launch_bounds__(256) void topmerge_kernel(
    const unsigned* __restrict__ pk, float* __restrict__ scores,
    int* __restrict__ sidx, int* __restrict__ hist) {
    __shared__ int lhist[NC];
    const int t = threadIdx.x;
    lhist[t] = 0; lhist[t + 256] = 0;
    __syncthreads();
    const int n = blockIdx.x * 256 + t;
    const unsigned* p = pk + (size_t)n * 64;
    unsigned h[4]; int pos[4];
    #pragma unroll
    for (int w = 0; w < 4; ++w) { pos[w] = 0; h[w] = p[w * 16]; }
    float vals[16]; int ids[16];
    #pragma unroll
    for (int r = 0; r < KSEL; ++r) {
        unsigned m = h[0];
        #pragma unroll
        for (int w = 1; w < 4; ++w) m = m > h[w] ? m : h[w];
        vals[r] = funkey(m);
        ids[r] = (int)(m & 511u);
        #pragma unroll
        for (int w = 0; w < 4; ++w) {
            if (h[w] == m) {
                ++pos[w];
                h[w] = (pos[w] < KSEL) ? p[w * 16 + pos[w]] : 0u;
            }
        }
    }
    float mx = vals[0];
    float e[16]; float sum = 0.f;
    #pragma unroll
    for (int r = 0; r < KSEL; ++r) { e[r] = __expf(vals[r] - mx); sum += e[r]; }
    float inv = 1.f / sum;
    #pragma unroll
    for (int q = 0; q < 4; ++q) {
        *(float4*)(scores + n * KSEL + 4 * q) =
            make_float4(e[4*q] * inv, e[4*q+1] * inv, e[4*q+2] * inv, e[4*q+3] * inv);
        *(int4*)(sidx + n * KSEL + 4 * q) =
            make_int4(ids[4*q], ids[4*q+1], ids[4*q+2], ids[4*q+3]);
    }
    #pragma unroll
    for (int r = 0; r < KSEL; ++r) atomicAdd(&lhist[ids[r]], 1);
    __syncthreads();
    { int hv = lhist[t]; if (hv) atomicAdd(&hist[t], hv); }
    { int hv = lhist[t + 256]; if (hv) atomicAdd(&hist[t + 256], hv); }
}

// ---------------- kernel P: scatter with fused per-block prefix scan ---------
__global__ __launch_bounds__(256) void scatter5_kernel(
    const int* __restrict__ hist, const int* __restrict__ sidx,
    const float* __restrict__ scores, int* __restrict__ cursor,
    int* __restrict__ tokentab, float* __restrict__ scotab,
    int* __restrict__ meta) {
    __shared__ int buf[2][NC];
    __shared__ int sb[NC];
    __shared__ int lh[NC];
    __shared__ int lbase[NC];
    const int t = threadIdx.x;

    // padded inclusive scan of hist (9 rounds, 2 elems/thread)
    int h0 = hist[t], h1 = hist[t + 256];
    int p0 = (h0 + 127) & ~127, p1 = (h1 + 127) & ~127;
    buf[0][t] = p0; buf[0][t + 256] = p1;
    __syncthreads();
    int a = 0;
    for (int d = 1; d < NC; d <<= 1) {
        int v0 = buf[a][t] + (t >= d ? buf[a][t - d] : 0);
        int v1 = buf[a][t + 256] + (t + 256 >= d ? buf[a][t + 256 - d] : 0);
        buf[1 - a][t] = v0; buf[1 - a][t + 256] = v1;
        __syncthreads();
        a ^= 1;
    }
    sb[t] = buf[a][t] - p0;
    sb[t + 256] = buf[a][t + 256] - p1;
    if (t == 255) meta[0] = buf[a][NC - 1];   // total (same in every block)
    lh[t] = 0; lh[t + 256] = 0;
    __syncthreads();

    const int base_e = blockIdx.x * 1024;
    int myc[4];
    #pragma unroll
    for (int i = 0; i < 4; ++i) {
        int c = sidx[base_e + t + 256 * i];
        myc[i] = c;
        atomicAdd(&lh[c], 1);
    }
    __syncthreads();
    for (int i = t; i < NC; i += 256) {
        int h = lh[i];
        lbase[i] = h ? (sb[i] + atomicAdd(&cursor[i], h)) : 0;
        lh[i] = 0;
    }
    __syncthreads();
    #pragma unroll
    for (int i = 0; i < 4; ++i) {
        int e = base_e + t + 256 * i;
        int c = myc[i];
        int pos = lbase[c] + atomicAdd(&lh[c], 1);
        tokentab[pos] = (c << 19) | e;
        scotab[pos] = scores[e];
    }
}

// ---------------- kernel C (fast): MFMA mix, bf16 inputs pre-staged ----------
// tokentab is center-sorted: 4-5 consecutive blocks share one 8KB Wbt panel.
// Bijective XCD swizzle (m204) co-locates them on one XCD's L2 -> panel
// fetched ~once per XCD instead of per block.
__global__ __launch_bounds__(256) void mix17_kernel(
    const unsigned short* __restrict__ xh, const unsigned short* __restrict__ wbt,
    const float* __restrict__ Ov, const int* __restrict__ tokentab,
    const float* __restrict__ scotab, const int* __restrict__ meta,
    __half* __restrict__ partial) {
    __shared__ __align__(16) unsigned short Wt[64 * 72];   // 9216 B
    __shared__ int eT[128];
    __shared__ float sT[128];

    const int t = threadIdx.x;
    // bijective XCD swizzle: nwg = 2556, q = 319, r = 4
    const int nwg = (int)gridDim.x;
    const int q = nwg >> 3, r = nwg & 7;
    const int xcd = (int)blockIdx.x & 7, idx = (int)blockIdx.x >> 3;
    const int swz = (xcd < r ? xcd * (q + 1) : r * (q + 1) + (xcd - r) * q) + idx;
    const int base = swz * 128;
    if (base >= meta[0]) return;               // block-uniform, before barriers

    const int c = (int)(((unsigned)tokentab[base]) >> 19);

    // stage Wt: pure copy from Wbt[c] (layout already [p][g])
    {
        const unsigned short* Wp = wbt + (size_t)c * 4096;
        const int p = t >> 2, qq = t & 3;
        *(ushort8*)(Wt + p * 72 + qq * 16) =
            *(const ushort8*)(Wp + p * 64 + qq * 16);
        *(ushort8*)(Wt + p * 72 + qq * 16 + 8) =
            *(const ushort8*)(Wp + p * 64 + qq * 16 + 8);
    }
    if (t < 128) {
        unsigned w = (unsigned)tokentab[base + t];
        eT[t] = (int)(w & 0x7FFFFu);           // pad -> 0x7FFFF (>= NPAIR)
        sT[t] = scotab[base + t];              // pad -> garbage: row-contained
    }
    __syncthreads();

    const int lane = t & 63;
    const int wv = t >> 6;
    const int mrow = lane & 31;
    const int half = lane >> 5;
    const int row = wv * 32 + mrow;

    const int mye = eT[row];
    const int myn = (mye < NPAIR) ? (mye >> 4) : 0;   // clamp pad gather

    const unsigned short* xp = xh + (size_t)myn * 64 + half * 8;
    short8 a[4];
    #pragma unroll
    for (int kt = 0; kt < 4; ++kt) a[kt] = *(const short8*)(xp + kt * 16);

    float16 acc0 = {0.f,0.f,0.f,0.f,0.f,0.f,0.f,0.f,0.f,0.f,0.f,0.f,0.f,0.f,0.f,0.f};
    float16 acc1 = {0.f,0.f,0.f,0.f,0.f,0.f,0.f,0.f,0.f,0.f,0.f,0.f,0.f,0.f,0.f,0.f};

    const unsigned short* B0 = Wt + mrow * 72;
    const unsigned short* B1 = Wt + (mrow + 32) * 72;
    #pragma unroll
    for (int kt = 0; kt < 4; ++kt) {
        short8 b0 = *(const short8*)(B0 + kt * 16 + half * 8);
        short8 b1 = *(const short8*)(B1 + kt * 16 + half * 8);
        acc0 = __builtin_amdgcn_mfma_f32_32x32x16_bf16(a[kt], b0, acc0, 0, 0, 0);
        acc1 = __builtin_amdgcn_mfma_f32_32x32x16_bf16(a[kt], b1, acc1, 0, 0, 0);
    }

    const float ov0 = Ov[c * D + mrow];
    const float ov1 = Ov[c * D + 32 + mrow];
    #pragma unroll
    for (int reg = 0; reg < 16; ++reg) {
        int orow = wv * 32 + (reg & 3) + 8 * (reg >> 2) + 4 * half;
        float s = sT[orow];
        int e = eT[orow];
        if (e < NPAIR) {                       // pad rows: no stores
            __half* dst = partial + (size_t)e * D;
            dst[mrow]      = __float2half(s * (acc0[reg] + ov0));
            dst[32 + mrow] = __float2half(s * (acc1[reg] + ov1));
        }
    }
}

// ---------------- kernel R: per-token reduce of 16 fp16 contributions --------
__global__ __launch_bounds__(256) void redu2_kernel(
    const __half* __restrict__ partial, float* __restrict__ out) {
    const int g = blockIdx.x * 256 + threadIdx.x;   // N_TOK*8 threads
    const int n = g >> 3;
    const int d8 = (g & 7) * 8;
    const __half* p = partial + (size_t)n * (KSEL * D) + d8;
    float s[8] = {0.f, 0.f, 0.f, 0.f, 0.f, 0.f, 0.f, 0.f};
    #pragma unroll
    for (int r = 0; r < KSEL; ++r) {
        ushort8 v = *(const ushort8*)(p + r * D);
        #pragma unroll
        for (int j = 0; j < 8; ++j)
            s[j] += __half2float(__ushort_as_half((unsigned short)v[j]));
    }
    float* o = out + n * D + d8;
    *(float4*)(o)     = make_float4(s[0], s[1], s[2], s[3]);
    *(float4*)(o + 4) = make_float4(s[4], s[5], s[6], s[7]);
}

// ---------------- kernel C (fallback): original atomic epilogue ---------------
__global__ __launch_bounds__(256) void mix14_kernel(
    const float* __restrict__ x, const float* __restrict__ Wv,
    const float* __restrict__ Ov, const int* __restrict__ tokentab,
    const float* __restrict__ scotab, const int* __restrict__ meta,
    float* __restrict__ out) {
    __shared__ __align__(16) unsigned short Wt[64 * 72];
    __shared__ int tT[128];
    __shared__ float sT[128];

    const int t = threadIdx.x;
    const int base = blockIdx.x * 128;
    if (base >= meta[0]) return;

    const int c = (int)(((unsigned)tokentab[base]) >> 19);

    {
        const float* Wp = Wv + c * (D * D) + (t & 63);
        const int gb = (t >> 6) * 16;
        #pragma unroll
        for (int g = 0; g < 16; g += 2) {
            float v0 = Wp[(gb + g) * 64];
            float v1 = Wp[(gb + g + 1) * 64];
            unsigned pkw = (unsigned)bfr(v0) | ((unsigned)bfr(v1) << 16);
            *(unsigned*)&Wt[(t & 63) * 72 + gb + g] = pkw;
        }
    }
    if (t < 128) {
        unsigned w = (unsigned)tokentab[base + t];
        tT[t] = (int)((w & 0x7FFFFu) >> 4);    // pad (memset 0) -> token 0
        sT[t] = scotab[base + t];
    }
    __syncthreads();

    const int lane = t & 63;
    const int wv = t >> 6;
    const int mrow = lane & 31;
    const int half = lane >> 5;
    const int row = wv * 32 + mrow;

    const int   myn = tT[row];
    const float mys = sT[row];

    const float* xp = x + myn * D + half * 8;
    float4 f[8];
    #pragma unroll
    for (int kt = 0; kt < 4; ++kt) {
        f[2 * kt]     = *(const float4*)(xp + kt * 16);
        f[2 * kt + 1] = *(const float4*)(xp + kt * 16 + 4);
    }
    short8 a[4];
    #pragma unroll
    for (int kt = 0; kt < 4; ++kt) {
        float4 u = f[2 * kt], v = f[2 * kt + 1];
        a[kt][0] = (short)bfr(u.x * mys); a[kt][1] = (short)bfr(u.y * mys);
        a[kt][2] = (short)bfr(u.z * mys); a[kt][3] = (short)bfr(u.w * mys);
        a[kt][4] = (short)bfr(v.x * mys); a[kt][5] = (short)bfr(v.y * mys);
        a[kt][6] = (short)bfr(v.z * mys); a[kt][7] = (short)bfr(v.w * mys);
    }

    float16 acc0 = {0.f,0.f,0.f,0.f,0.f,0.f,0.f,0.f,0.f,0.f,0.f,0.f,0.f,0.f,0.f,0.f};
    float16 acc1 = {0.f,0.f,0.f,0.f,0.f,0.f,0.f,0.f,0.f,0.f,0.f,0.f,0.f,0.f,0.f,0.f};

    const unsigned short* B0 = Wt + mrow * 72;
    const unsigned short* B1 = Wt + (mrow + 32) * 72;
    #pragma unroll
    for (int kt = 0; kt < 4; ++kt) {
        short8 b0 = *(const short8*)(B0 + kt * 16 + half * 8);
        short8 b1 = *(const short8*)(B1 + kt * 16 + half * 8);
        acc0 = __builtin_amdgcn_mfma_f32_32x32x16_bf16(a[kt], b0, acc0, 0, 0, 0);
        acc1 = __builtin_amdgcn_mfma_f32_32x32x16_bf16(a[kt], b1, acc1, 0, 0, 0);
    }

    const float ov0 = Ov[c * D + mrow];
    const float ov1 = Ov[c * D + 32 + mrow];
    #pragma unroll
    for (int reg = 0; reg < 16; ++reg) {
        int orow = wv * 32 + (reg & 3) + 8 * (reg >> 2) + 4 * half;
        float s = sT[orow];
        if (s != 0.f) {
            int n = tT[orow];
            unsafeAtomicAdd(out + n * D + mrow,      acc0[reg] + s * ov0);
            unsafeAtomicAdd(out + n * D + 32 + mrow, acc1[reg] + s * ov1);
        }
    }
}

extern "C" void kernel_launch(void* const* d_in, const int* in_sizes, int n_in,
                              void* d_out, int out_size, void* d_ws, size_t ws_size,
                              hipStream_t stream) {
    const float* x    = (const float*)d_in[0];
    const float* ctrs = (const float*)d_in[1];
    const float* Wv   = (const float*)d_in[2];
    const float* Ov   = (const float*)d_in[3];
    float* out = (float*)d_out;

    // workspace layout (int offsets)
    const size_t OFF_META = 0;                       // 512
    const size_t OFF_HIST = 512;                     // 512
    const size_t OFF_CUR  = 1024;                    // 512 (adjacent to hist)
    const size_t OFF_SCO  = 2560;                    // NPAIR
    const size_t OFF_SIDX = OFF_SCO + NPAIR;         // NPAIR
    const size_t OFF_TTAB = OFF_SIDX + NPAIR;        // PADCAP
    const size_t OFF_STAB = OFF_TTAB + PADCAP;       // PADCAP
    const size_t PK_INTS  = (size_t)N_TOK * 64;
    const size_t XH_INTS  = (size_t)N_TOK * 32;      // N_TOK*64 bf16
    const size_t CBF_INTS = (size_t)NC * 68;         // 512*136 bf16
    const size_t WBT_INTS = (size_t)NC * 2048;       // 512*4096 bf16
    const size_t O_PK   = OFF_STAB + PADCAP;
    const size_t O_XH   = O_PK + PK_INTS;
    const size_t O_XL   = O_XH + XH_INTS;
    const size_t O_CBF  = O_XL + XH_INTS;
    const size_t O_C2   = O_CBF + CBF_INTS;
    const size_t O_WBT  = O_C2 + 512;
    const size_t O_PART = O_WBT + WBT_INTS;
    const size_t PART_INTS = (size_t)NPAIR * 32;     // NPAIR*64 halves

    int*    meta     = (int*)d_ws + OFF_META;
    int*    hist     = (int*)d_ws + OFF_HIST;
    int*    cursor   = (int*)d_ws + OFF_CUR;
    float*  scores   = (float*)d_ws + OFF_SCO;
    int*    sidx     = (int*)d_ws + OFF_SIDX;
    int*    tokentab = (int*)d_ws + OFF_TTAB;
    float*  scotab   = (float*)d_ws + OFF_STAB;
    unsigned* pkbuf  = (unsigned*)((int*)d_ws + O_PK);
    unsigned short* xh  = (unsigned short*)((int*)d_ws + O_XH);
    unsigned short* xl  = (unsigned short*)((int*)d_ws + O_XL);
    unsigned short* cbf = (unsigned short*)((int*)d_ws + O_CBF);
    float*  c2g      = (float*)((int*)d_ws + O_C2);
    unsigned short* wbt = (unsigned short*)((int*)d_ws + O_WBT);
    __half* partial  = (__half*)((int*)d_ws + O_PART);

    const size_t need = (O_PART + PART_INTS) * 4;
    const bool fast = ws_size >= need;

    // prep2 does all table inits (tokentab=-1, hist/cursor=0) + splits + Wbt
    hipLaunchKernelGGL(prep2_kernel, dim3(1349), dim3(256), 0, stream,
                       x, ctrs, Wv, xh, xl, cbf, c2g, wbt, tokentab, hist);
    if (!fast) {
        // fallback expects tokentab=0 pads, zeroed scotab and out
        hipMemsetAsync(out, 0, (size_t)N_TOK * D * sizeof(float), stream);
        hipMemsetAsync(scotab, 0, (size_t)PADCAP * sizeof(float), stream);
        hipMemsetAsync(tokentab, 0, (size_t)PADCAP * sizeof(int), stream);
    }
    hipLaunchKernelGGL(topk15_kernel, dim3((N_TOK / 64) * 4), dim3(256), 0, stream,
                       xh, xl, cbf, c2g, pkbuf);
    hipLaunchKernelGGL(topmerge_kernel, dim3(N_TOK / 256), dim3(256), 0, stream,
                       pkbuf, scores, sidx, hist);
    hipLaunchKernelGGL(scatter5_kernel, dim3(256), dim3(256), 0, stream,
                       hist, sidx, scores, cursor, tokentab, scotab, meta);
    if (fast) {
        hipLaunchKernelGGL(mix17_kernel, dim3(PADCAP / 128), dim3(256), 0, stream,
                           xh, wbt, Ov, tokentab, scotab, meta, partial);
        hipLaunchKernelGGL(redu2_kernel, dim3(N_TOK * 8 / 256), dim3(256), 0, stream,
                           partial, out);
    } else {
        hipLaunchKernelGGL(mix14_kernel, dim3(PADCAP / 128), dim3(256), 0, stream,
                           x, Wv, Ov, tokentab, scotab, meta, out);
    }
}

// Round 10
// 134.405 us; speedup vs baseline: 1.0951x; 1.0231x over previous
//
#include <hip/hip_runtime.h>
#include <hip/hip_fp16.h>

#define N_TOK 16384
#define D 64
#define NC 512
#define KSEL 16
#define NPAIR (N_TOK * KSEL)   // 262144 real (token,rank) pairs
#define PADCAP 327168          // 262144 + 512*127: per-center segments padded to 128

typedef __attribute__((ext_vector_type(8))) short short8;
typedef __attribute__((ext_vector_type(8))) unsigned short ushort8;
typedef __attribute__((ext_vector_type(16))) float float16;

__device__ __forceinline__ unsigned fkey(float f) {
    unsigned u = __float_as_uint(f);
    return (u & 0x80000000u) ? ~u : (u | 0x80000000u);
}
__device__ __forceinline__ float funkey(unsigned k) {
    unsigned u = (k & 0x80000000u) ? (k & 0x7fffffffu) : ~k;
    return __uint_as_float(u);
}
__device__ __forceinline__ unsigned short bfr(float f) {  // fp32 -> bf16 RNE
    unsigned u = __float_as_uint(f);
    return (unsigned short)((u + 0x7FFFu + ((u >> 16) & 1u)) >> 16);
}
__device__ __forceinline__ float b2f(unsigned short h) {  // bf16 -> fp32
    return __uint_as_float((unsigned)h << 16);
}

__device__ __forceinline__ void ins16(unsigned (&run)[16], unsigned k) {
    #pragma unroll
    for (int r = 0; r < 16; ++r) {
        unsigned mx = run[r] > k ? run[r] : k;
        unsigned mn = run[r] > k ? k : run[r];
        run[r] = mx; k = mn;
    }
}

// ---------------- kernel Z: prep (splits + Wv transpose + table inits) -------
__global__ __launch_bounds__(256) void prep2_kernel(
    const float* __restrict__ x, const float* __restrict__ ctrs,
    const float* __restrict__ Wv,
    unsigned short* __restrict__ xh, unsigned short* __restrict__ xl,
    unsigned short* __restrict__ cbf, float* __restrict__ c2g,
    unsigned short* __restrict__ wbt, int* __restrict__ tokentab,
    int* __restrict__ hist) {
    __shared__ unsigned short tw[64 * 68];
    const int b = blockIdx.x, t = threadIdx.x;
    if (b < 512) {            // x rows: thread splits 8 dims
        int g = b * 256 + t;
        int row = g >> 3, seg = g & 7;
        const float4* xp = (const float4*)(x + row * 64 + seg * 8);
        float4 u = xp[0], v = xp[1];
        float c[8] = {u.x, u.y, u.z, u.w, v.x, v.y, v.z, v.w};
        ushort8 h, l;
        #pragma unroll
        for (int j = 0; j < 8; ++j) {
            h[j] = bfr(c[j]);
            l[j] = bfr(c[j] - b2f(h[j]));
        }
        *(ushort8*)(xh + row * 64 + seg * 8) = h;
        *(ushort8*)(xl + row * 64 + seg * 8) = l;
    } else if (b < 516) {     // ctrs: 2 threads per center (q = 32-dim half)
        int g = (b - 512) * 256 + t;   // 0..1023
        int c = g >> 1, q = g & 1;
        const float4* cp = (const float4*)(ctrs + c * D + q * 32);
        unsigned short* Ch = cbf + c * 136 + q * 32;
        float s2 = 0.f;
        #pragma unroll
        for (int i = 0; i < 8; ++i) {
            float4 v = cp[i];
            s2 += v.x * v.x + v.y * v.y + v.z * v.z + v.w * v.w;
            unsigned short h0 = bfr(v.x), h1 = bfr(v.y), h2 = bfr(v.z), h3 = bfr(v.w);
            unsigned short l0 = bfr(v.x - b2f(h0)), l1 = bfr(v.y - b2f(h1));
            unsigned short l2 = bfr(v.z - b2f(h2)), l3 = bfr(v.w - b2f(h3));
            *(uint2*)(Ch + 4 * i) =
                make_uint2((unsigned)h0 | ((unsigned)h1 << 16),
                           (unsigned)h2 | ((unsigned)h3 << 16));
            *(uint2*)(Ch + 64 + 4 * i) =
                make_uint2((unsigned)l0 | ((unsigned)l1 << 16),
                           (unsigned)l2 | ((unsigned)l3 << 16));
        }
        s2 += __shfl_xor(s2, 1);
        c2g[c] = s2;          // both q-threads write same value: benign
    } else if (b < 1028) {    // Wv transpose via LDS: Wbt[c][p][g] = W[c][g][p]
        const float* Wp = Wv + (size_t)(b - 516) * 4096;
        #pragma unroll
        for (int i = 0; i < 16; ++i) {
            int e = t + 256 * i;           // e = g*64 + p
            tw[(e & 63) * 68 + (e >> 6)] = bfr(Wp[e]);
        }
        __syncthreads();
        unsigned short* Wo = wbt + (size_t)(b - 516) * 4096;
        #pragma unroll
        for (int i = 0; i < 2; ++i) {
            int idx8 = t + 256 * i;        // ushort8 index
            int p = idx8 >> 3, g0 = (idx8 & 7) * 8;
            ushort8 v;
            #pragma unroll
            for (int j = 0; j < 8; ++j) v[j] = tw[p * 68 + g0 + j];
            *(ushort8*)(Wo + idx8 * 8) = v;
        }
    } else if (b < 1348) {    // tokentab -1 fill (81792 int4)
        int i = (b - 1028) * 256 + t;
        if (i < PADCAP / 4) ((int4*)tokentab)[i] = make_int4(-1, -1, -1, -1);
    } else {                  // hist[512] + cursor[512] zero (adjacent)
        hist[t] = 0; hist[t + 256] = 0; hist[t + 512] = 0; hist[t + 768] = 0;
    }
}

// ---------------- kernel B: dist via bf16-split MFMA + per-phase top-16 ------
// R7-verified structure: 4 blocks/CU phase-split grid. Fusion (R8) regressed
// -13us (2 blocks/CU barrier convoy); per-lane threshold guard (R9) was null
// (wave-predicated: chain runs if ANY lane passes). This is the measured
// optimum configuration.
__global__ __launch_bounds__(256, 4) void topk15_kernel(
    const unsigned short* __restrict__ xh, const unsigned short* __restrict__ xl,
    const unsigned short* __restrict__ cbf, const float* __restrict__ c2g,
    unsigned* __restrict__ pk) {
    __shared__ __align__(16) unsigned char pool[35328];
    unsigned short* Cbf = (unsigned short*)pool;   // [128 ctr][136]: 0..63 ch, 64..127 cl
    unsigned* Sbk = (unsigned*)pool;               // overlay [64 tok][132] keys
    unsigned* mbp = (unsigned*)pool;               // overlay [64 tok][68]
    float* c2s = (float*)(pool + 34816);           // [128] ||c||^2

    const int t = threadIdx.x;
    const int lane = t & 63;
    const int wv = t >> 6;               // wave 0..3
    const int mrow = lane & 31;
    const int half = lane >> 5;
    const int tb = blockIdx.x >> 2;
    const int p = blockIdx.x & 3;
    const int base = tb * 64;
    const int cbase = p * 128;
    const int trow = (wv & 1) * 32;      // token-row group of this wave
    const int cgrp = (wv >> 1) * 64;     // ctr-col group base of this wave

    // ---- stage C: pure copy, 34816 B = 2176 uint4 ----
    {
        const uint4* src = (const uint4*)(cbf + (size_t)cbase * 136);
        uint4* dst = (uint4*)pool;
        #pragma unroll
        for (int i = 0; i < 8; ++i) dst[t + 256 * i] = src[t + 256 * i];
        if (t < 128) {
            dst[2048 + t] = src[2048 + t];
            c2s[t] = c2g[cbase + t];
        }
    }

    // ---- A frags: direct bf16 loads ----
    short8 ah[4], al[4];
    {
        const int xrow = base + trow + mrow;
        const unsigned short* xph = xh + (size_t)xrow * 64 + half * 8;
        const unsigned short* xpl = xl + (size_t)xrow * 64 + half * 8;
        #pragma unroll
        for (int kt = 0; kt < 4; ++kt) {
            ah[kt] = *(const short8*)(xph + kt * 16);
            al[kt] = *(const short8*)(xpl + kt * 16);
        }
    }
    __syncthreads();   // (1) Cbf/c2s staged

    float16 acc0 = {0.f,0.f,0.f,0.f,0.f,0.f,0.f,0.f,0.f,0.f,0.f,0.f,0.f,0.f,0.f,0.f};
    float16 acc1 = acc0;

    const unsigned short* B0 = Cbf + (cgrp + mrow) * 136 + half * 8;
    const unsigned short* B1 = Cbf + (cgrp + 32 + mrow) * 136 + half * 8;
    #pragma unroll
    for (int kt = 0; kt < 4; ++kt) {
        short8 bh0 = *(const short8*)(B0 + kt * 16);
        short8 bh1 = *(const short8*)(B1 + kt * 16);
        short8 bl0 = *(const short8*)(B0 + 64 + kt * 16);
        short8 bl1 = *(const short8*)(B1 + 64 + kt * 16);
        acc0 = __builtin_amdgcn_mfma_f32_32x32x16_bf16(ah[kt], bh0, acc0, 0, 0, 0);
        acc1 = __builtin_amdgcn_mfma_f32_32x32x16_bf16(ah[kt], bh1, acc1, 0, 0, 0);
        acc0 = __builtin_amdgcn_mfma_f32_32x32x16_bf16(al[kt], bh0, acc0, 0, 0, 0);
        acc1 = __builtin_amdgcn_mfma_f32_32x32x16_bf16(al[kt], bh1, acc1, 0, 0, 0);
        acc0 = __builtin_amdgcn_mfma_f32_32x32x16_bf16(ah[kt], bl0, acc0, 0, 0, 0);
        acc1 = __builtin_amdgcn_mfma_f32_32x32x16_bf16(ah[kt], bl1, acc1, 0, 0, 0);
    }
    __syncthreads();   // (2) Cbf reads done -> Sbk overlay safe

    // ---- keygen: all 128 ctr keys per token staged at once ----
    {
        float ca = c2s[cgrp + mrow];
        float cb = c2s[cgrp + 32 + mrow];
        #pragma unroll
        for (int reg = 0; reg < 16; ++reg) {
            int tokrow = trow + (reg & 3) + 8 * (reg >> 2) + 4 * half;
            float sa = fmaf(2.f, acc0[reg], -ca);
            float sb = fmaf(2.f, acc1[reg], -cb);
            Sbk[tokrow * 132 + cgrp + mrow] =
                (fkey(sa) & 0xFFFFFE00u) | (unsigned)(cbase + cgrp + mrow);
            Sbk[tokrow * 132 + cgrp + 32 + mrow] =
                (fkey(sb) & 0xFFFFFE00u) | (unsigned)(cbase + cgrp + 32 + mrow);
        }
    }
    __syncthreads();   // (3) keys staged

    // ---- selection: thread t -> token t&63, ctr-quarter t>>6 (32 keys) ----
    const int tok = t & 63;
    const int h = t >> 6;
    unsigned run[16];
    #pragma unroll
    for (int r = 0; r < 16; ++r) run[r] = 0u;
    #pragma unroll
    for (int i = 0; i < 8; ++i) {
        int cq = ((i + tok) & 7) ^ ((tok >> 3) & 7);   // bank-spread rotation
        uint4 kv = *(const uint4*)(Sbk + tok * 132 + 32 * h + 4 * cq);
        ins16(run, kv.x); ins16(run, kv.y); ins16(run, kv.z); ins16(run, kv.w);
    }
    __syncthreads();   // (4) Sbk dead -> mbp overlay safe

    {
        uint4* dst = (uint4*)(mbp + tok * 68 + h * 16);
        dst[0] = make_uint4(run[0], run[1], run[2], run[3]);
        dst[1] = make_uint4(run[4], run[5], run[6], run[7]);
        dst[2] = make_uint4(run[8], run[9], run[10], run[11]);
        dst[3] = make_uint4(run[12], run[13], run[14], run[15]);
    }
    __syncthreads();   // (5)

    if (t < 64) {      // 4-way tournament merge -> phase top-16, write pk
        const unsigned* pm = mbp + t * 68;
        unsigned hv[4]; int pos[4];
        #pragma unroll
        for (int w = 0; w < 4; ++w) { pos[w] = 0; hv[w] = pm[w * 16]; }
        unsigned mm[16];
        #pragma unroll
        for (int r = 0; r < 16; ++r) {
            unsigned m = hv[0];
            #pragma unroll
            for (int w = 1; w < 4; ++w) m = m > hv[w] ? m : hv[w];
            mm[r] = m;
            #pragma unroll
            for (int w = 0; w < 4; ++w) {
                if (hv[w] == m) {
                    ++pos[w];
                    hv[w] = (pos[w] < 16) ? pm[w * 16 + pos[w]] : 0u;
                }
            }
        }
        uint4* dst = (uint4*)(pk + (size_t)(base + t) * 64 + p * 16);
        dst[0] = make_uint4(mm[0], mm[1], mm[2], mm[3]);
        dst[1] = make_uint4(mm[4], mm[5], mm[6], mm[7]);
        dst[2] = make_uint4(mm[8], mm[9], mm[10], mm[11]);
        dst[3] = make_uint4(mm[12], mm[13], mm[14], mm[15]);
    }
}

// ---------------- kernel M: 4-way cross-phase merge + softmax + hist ---------
__global__ __launch_bounds__(256) void topmerge_kernel(
    const unsigned* __restrict__ pk, float* __restrict__ scores,
    int* __restrict__ sidx, int* __restrict__ hist) {
    __shared__ int lhist[NC];
    const int t = threadIdx.x;
    lhist[t] = 0; lhist[t + 256] = 0;
    __syncthreads();
    const int n = blockIdx.x * 256 + t;
    const unsigned* p = pk + (size_t)n * 64;
    unsigned h[4]; int pos[4];
    #pragma unroll
    for (int w = 0; w < 4; ++w) { pos[w] = 0; h[w] = p[w * 16]; }
    float vals[16]; int ids[16];
    #pragma unroll
    for (int r = 0; r < KSEL; ++r) {
        unsigned m = h[0];
        #pragma unroll
        for (int w = 1; w < 4; ++w) m = m > h[w] ? m : h[w];
        vals[r] = funkey(m);
        ids[r] = (int)(m & 511u);
        #pragma unroll
        for (int w = 0; w < 4; ++w) {
            if (h[w] == m) {
                ++pos[w];
                h[w] = (pos[w] < KSEL) ? p[w * 16 + pos[w]] : 0u;
            }
        }
    }
    float mx = vals[0];
    float e[16]; float sum = 0.f;
    #pragma unroll
    for (int r = 0; r < KSEL; ++r) { e[r] = __expf(vals[r] - mx); sum += e[r]; }
    float inv = 1.f / sum;
    #pragma unroll
    for (int q = 0; q < 4; ++q) {
        *(float4*)(scores + n * KSEL + 4 * q) =
            make_float4(e[4*q] * inv, e[4*q+1] * inv, e[4*q+2] * inv, e[4*q+3] * inv);
        *(int4*)(sidx + n * KSEL + 4 * q) =
            make_int4(ids[4*q], ids[4*q+1], ids[4*q+2], ids[4*q+3]);
    }
    #pragma unroll
    for (int r = 0; r < KSEL; ++r) atomicAdd(&lhist[ids[r]], 1);
    __syncthreads();
    { int hv = lhist[t]; if (hv) atomicAdd(&hist[t], hv); }
    { int hv = lhist[t + 256]; if (hv) atomicAdd(&hist[t + 256], hv); }
}

// ---------------- kernel P: scatter with fused per-block prefix scan ---------
__global__ __launch_bounds__(256) void scatter5_kernel(
    const int* __restrict__ hist, const int* __restrict__ sidx,
    const float* __restrict__ scores, int* __restrict__ cursor,
    int* __restrict__ tokentab, float* __restrict__ scotab,
    int* __restrict__ meta) {
    __shared__ int buf[2][NC];
    __shared__ int sb[NC];
    __shared__ int lh[NC];
    __shared__ int lbase[NC];
    const int t = threadIdx.x;

    // padded inclusive scan of hist (9 rounds, 2 elems/thread)
    int h0 = hist[t], h1 = hist[t + 256];
    int p0 = (h0 + 127) & ~127, p1 = (h1 + 127) & ~127;
    buf[0][t] = p0; buf[0][t + 256] = p1;
    __syncthreads();
    int a = 0;
    for (int d = 1; d < NC; d <<= 1) {
        int v0 = buf[a][t] + (t >= d ? buf[a][t - d] : 0);
        int v1 = buf[a][t + 256] + (t + 256 >= d ? buf[a][t + 256 - d] : 0);
        buf[1 - a][t] = v0; buf[1 - a][t + 256] = v1;
        __syncthreads();
        a ^= 1;
    }
    sb[t] = buf[a][t] - p0;
    sb[t + 256] = buf[a][t + 256] - p1;
    if (t == 255) meta[0] = buf[a][NC - 1];   // total (same in every block)
    lh[t] = 0; lh[t + 256] = 0;
    __syncthreads();

    const int base_e = blockIdx.x * 1024;
    int myc[4];
    #pragma unroll
    for (int i = 0; i < 4; ++i) {
        int c = sidx[base_e + t + 256 * i];
        myc[i] = c;
        atomicAdd(&lh[c], 1);
    }
    __syncthreads();
    for (int i = t; i < NC; i += 256) {
        int h = lh[i];
        lbase[i] = h ? (sb[i] + atomicAdd(&cursor[i], h)) : 0;
        lh[i] = 0;
    }
    __syncthreads();
    #pragma unroll
    for (int i = 0; i < 4; ++i) {
        int e = base_e + t + 256 * i;
        int c = myc[i];
        int pos = lbase[c] + atomicAdd(&lh[c], 1);
        tokentab[pos] = (c << 19) | e;
        scotab[pos] = scores[e];
    }
}

// ---------------- kernel C (fast): MFMA mix, bf16 inputs pre-staged ----------
// (R9's XCD swizzle removed: wbt is 4MB = L3-resident, mechanism's regime
// absent, measured null-to-negative.)
__global__ __launch_bounds__(256) void mix17_kernel(
    const unsigned short* __restrict__ xh, const unsigned short* __restrict__ wbt,
    const float* __restrict__ Ov, const int* __restrict__ tokentab,
    const float* __restrict__ scotab, const int* __restrict__ meta,
    __half* __restrict__ partial) {
    __shared__ __align__(16) unsigned short Wt[64 * 72];   // 9216 B
    __shared__ int eT[128];
    __shared__ float sT[128];

    const int t = threadIdx.x;
    const int base = blockIdx.x * 128;
    if (base >= meta[0]) return;               // block-uniform, before barriers

    const int c = (int)(((unsigned)tokentab[base]) >> 19);

    // stage Wt: pure copy from Wbt[c] (layout already [p][g])
    {
        const unsigned short* Wp = wbt + (size_t)c * 4096;
        const int p = t >> 2, qq = t & 3;
        *(ushort8*)(Wt + p * 72 + qq * 16) =
            *(const ushort8*)(Wp + p * 64 + qq * 16);
        *(ushort8*)(Wt + p * 72 + qq * 16 + 8) =
            *(const ushort8*)(Wp + p * 64 + qq * 16 + 8);
    }
    if (t < 128) {
        unsigned w = (unsigned)tokentab[base + t];
        eT[t] = (int)(w & 0x7FFFFu);           // pad -> 0x7FFFF (>= NPAIR)
        sT[t] = scotab[base + t];              // pad -> garbage: row-contained
    }
    __syncthreads();

    const int lane = t & 63;
    const int wv = t >> 6;
    const int mrow = lane & 31;
    const int half = lane >> 5;
    const int row = wv * 32 + mrow;

    const int mye = eT[row];
    const int myn = (mye < NPAIR) ? (mye >> 4) : 0;   // clamp pad gather

    const unsigned short* xp = xh + (size_t)myn * 64 + half * 8;
    short8 a[4];
    #pragma unroll
    for (int kt = 0; kt < 4; ++kt) a[kt] = *(const short8*)(xp + kt * 16);

    float16 acc0 = {0.f,0.f,0.f,0.f,0.f,0.f,0.f,0.f,0.f,0.f,0.f,0.f,0.f,0.f,0.f,0.f};
    float16 acc1 = {0.f,0.f,0.f,0.f,0.f,0.f,0.f,0.f,0.f,0.f,0.f,0.f,0.f,0.f,0.f,0.f};

    const unsigned short* B0 = Wt + mrow * 72;
    const unsigned short* B1 = Wt + (mrow + 32) * 72;
    #pragma unroll
    for (int kt = 0; kt < 4; ++kt) {
        short8 b0 = *(const short8*)(B0 + kt * 16 + half * 8);
        short8 b1 = *(const short8*)(B1 + kt * 16 + half * 8);
        acc0 = __builtin_amdgcn_mfma_f32_32x32x16_bf16(a[kt], b0, acc0, 0, 0, 0);
        acc1 = __builtin_amdgcn_mfma_f32_32x32x16_bf16(a[kt], b1, acc1, 0, 0, 0);
    }

    const float ov0 = Ov[c * D + mrow];
    const float ov1 = Ov[c * D + 32 + mrow];
    #pragma unroll
    for (int reg = 0; reg < 16; ++reg) {
        int orow = wv * 32 + (reg & 3) + 8 * (reg >> 2) + 4 * half;
        float s = sT[orow];
        int e = eT[orow];
        if (e < NPAIR) {                       // pad rows: no stores
            __half* dst = partial + (size_t)e * D;
            dst[mrow]      = __float2half(s * (acc0[reg] + ov0));
            dst[32 + mrow] = __float2half(s * (acc1[reg] + ov1));
        }
    }
}

// ---------------- kernel R: per-token reduce of 16 fp16 contributions --------
__global__ __launch_bounds__(256) void redu2_kernel(
    const __half* __restrict__ partial, float* __restrict__ out) {
    const int g = blockIdx.x * 256 + threadIdx.x;   // N_TOK*8 threads
    const int n = g >> 3;
    const int d8 = (g & 7) * 8;
    const __half* p = partial + (size_t)n * (KSEL * D) + d8;
    float s[8] = {0.f, 0.f, 0.f, 0.f, 0.f, 0.f, 0.f, 0.f};
    #pragma unroll
    for (int r = 0; r < KSEL; ++r) {
        ushort8 v = *(const ushort8*)(p + r * D);
        #pragma unroll
        for (int j = 0; j < 8; ++j)
            s[j] += __half2float(__ushort_as_half((unsigned short)v[j]));
    }
    float* o = out + n * D + d8;
    *(float4*)(o)     = make_float4(s[0], s[1], s[2], s[3]);
    *(float4*)(o + 4) = make_float4(s[4], s[5], s[6], s[7]);
}

// ---------------- kernel C (fallback): original atomic epilogue ---------------
__global__ __launch_bounds__(256) void mix14_kernel(
    const float* __restrict__ x, const float* __restrict__ Wv,
    const float* __restrict__ Ov, const int* __restrict__ tokentab,
    const float* __restrict__ scotab, const int* __restrict__ meta,
    float* __restrict__ out) {
    __shared__ __align__(16) unsigned short Wt[64 * 72];
    __shared__ int tT[128];
    __shared__ float sT[128];

    const int t = threadIdx.x;
    const int base = blockIdx.x * 128;
    if (base >= meta[0]) return;

    const int c = (int)(((unsigned)tokentab[base]) >> 19);

    {
        const float* Wp = Wv + c * (D * D) + (t & 63);
        const int gb = (t >> 6) * 16;
        #pragma unroll
        for (int g = 0; g < 16; g += 2) {
            float v0 = Wp[(gb + g) * 64];
            float v1 = Wp[(gb + g + 1) * 64];
            unsigned pkw = (unsigned)bfr(v0) | ((unsigned)bfr(v1) << 16);
            *(unsigned*)&Wt[(t & 63) * 72 + gb + g] = pkw;
        }
    }
    if (t < 128) {
        unsigned w = (unsigned)tokentab[base + t];
        tT[t] = (int)((w & 0x7FFFFu) >> 4);    // pad (memset 0) -> token 0
        sT[t] = scotab[base + t];
    }
    __syncthreads();

    const int lane = t & 63;
    const int wv = t >> 6;
    const int mrow = lane & 31;
    const int half = lane >> 5;
    const int row = wv * 32 + mrow;

    const int   myn = tT[row];
    const float mys = sT[row];

    const float* xp = x + myn * D + half * 8;
    float4 f[8];
    #pragma unroll
    for (int kt = 0; kt < 4; ++kt) {
        f[2 * kt]     = *(const float4*)(xp + kt * 16);
        f[2 * kt + 1] = *(const float4*)(xp + kt * 16 + 4);
    }
    short8 a[4];
    #pragma unroll
    for (int kt = 0; kt < 4; ++kt) {
        float4 u = f[2 * kt], v = f[2 * kt + 1];
        a[kt][0] = (short)bfr(u.x * mys); a[kt][1] = (short)bfr(u.y * mys);
        a[kt][2] = (short)bfr(u.z * mys); a[kt][3] = (short)bfr(u.w * mys);
        a[kt][4] = (short)bfr(v.x * mys); a[kt][5] = (short)bfr(v.y * mys);
        a[kt][6] = (short)bfr(v.z * mys); a[kt][7] = (short)bfr(v.w * mys);
    }

    float16 acc0 = {0.f,0.f,0.f,0.f,0.f,0.f,0.f,0.f,0.f,0.f,0.f,0.f,0.f,0.f,0.f,0.f};
    float16 acc1 = {0.f,0.f,0.f,0.f,0.f,0.f,0.f,0.f,0.f,0.f,0.f,0.f,0.f,0.f,0.f,0.f};

    const unsigned short* B0 = Wt + mrow * 72;
    const unsigned short* B1 = Wt + (mrow + 32) * 72;
    #pragma unroll
    for (int kt = 0; kt < 4; ++kt) {
        short8 b0 = *(const short8*)(B0 + kt * 16 + half * 8);
        short8 b1 = *(const short8*)(B1 + kt * 16 + half * 8);
        acc0 = __builtin_amdgcn_mfma_f32_32x32x16_bf16(a[kt], b0, acc0, 0, 0, 0);
        acc1 = __builtin_amdgcn_mfma_f32_32x32x16_bf16(a[kt], b1, acc1, 0, 0, 0);
    }

    const float ov0 = Ov[c * D + mrow];
    const float ov1 = Ov[c * D + 32 + mrow];
    #pragma unroll
    for (int reg = 0; reg < 16; ++reg) {
        int orow = wv * 32 + (reg & 3) + 8 * (reg >> 2) + 4 * half;
        float s = sT[orow];
        if (s != 0.f) {
            int n = tT[orow];
            unsafeAtomicAdd(out + n * D + mrow,      acc0[reg] + s * ov0);
            unsafeAtomicAdd(out + n * D + 32 + mrow, acc1[reg] + s * ov1);
        }
    }
}

extern "C" void kernel_launch(void* const* d_in, const int* in_sizes, int n_in,
                              void* d_out, int out_size, void* d_ws, size_t ws_size,
                              hipStream_t stream) {
    const float* x    = (const float*)d_in[0];
    const float* ctrs = (const float*)d_in[1];
    const float* Wv   = (const float*)d_in[2];
    const float* Ov   = (const float*)d_in[3];
    float* out = (float*)d_out;

    // workspace layout (int offsets)
    const size_t OFF_META = 0;                       // 512
    const size_t OFF_HIST = 512;                     // 512
    const size_t OFF_CUR  = 1024;                    // 512 (adjacent to hist)
    const size_t OFF_SCO  = 2560;                    // NPAIR
    const size_t OFF_SIDX = OFF_SCO + NPAIR;         // NPAIR
    const size_t OFF_TTAB = OFF_SIDX + NPAIR;        // PADCAP
    const size_t OFF_STAB = OFF_TTAB + PADCAP;       // PADCAP
    const size_t PK_INTS  = (size_t)N_TOK * 64;
    const size_t XH_INTS  = (size_t)N_TOK * 32;      // N_TOK*64 bf16
    const size_t CBF_INTS = (size_t)NC * 68;         // 512*136 bf16
    const size_t WBT_INTS = (size_t)NC * 2048;       // 512*4096 bf16
    const size_t O_PK   = OFF_STAB + PADCAP;
    const size_t O_XH   = O_PK + PK_INTS;
    const size_t O_XL   = O_XH + XH_INTS;
    const size_t O_CBF  = O_XL + XH_INTS;
    const size_t O_C2   = O_CBF + CBF_INTS;
    const size_t O_WBT  = O_C2 + 512;
    const size_t O_PART = O_WBT + WBT_INTS;
    const size_t PART_INTS = (size_t)NPAIR * 32;     // NPAIR*64 halves

    int*    meta     = (int*)d_ws + OFF_META;
    int*    hist     = (int*)d_ws + OFF_HIST;
    int*    cursor   = (int*)d_ws + OFF_CUR;
    float*  scores   = (float*)d_ws + OFF_SCO;
    int*    sidx     = (int*)d_ws + OFF_SIDX;
    int*    tokentab = (int*)d_ws + OFF_TTAB;
    float*  scotab   = (float*)d_ws + OFF_STAB;
    unsigned* pkbuf  = (unsigned*)((int*)d_ws + O_PK);
    unsigned short* xh  = (unsigned short*)((int*)d_ws + O_XH);
    unsigned short* xl  = (unsigned short*)((int*)d_ws + O_XL);
    unsigned short* cbf = (unsigned short*)((int*)d_ws + O_CBF);
    float*  c2g      = (float*)((int*)d_ws + O_C2);
    unsigned short* wbt = (unsigned short*)((int*)d_ws + O_WBT);
    __half* partial  = (__half*)((int*)d_ws + O_PART);

    const size_t need = (O_PART + PART_INTS) * 4;
    const bool fast = ws_size >= need;

    // prep2 does all table inits (tokentab=-1, hist/cursor=0) + splits + Wbt
    hipLaunchKernelGGL(prep2_kernel, dim3(1349), dim3(256), 0, stream,
                       x, ctrs, Wv, xh, xl, cbf, c2g, wbt, tokentab, hist);
    if (!fast) {
        // fallback expects tokentab=0 pads, zeroed scotab and out
        hipMemsetAsync(out, 0, (size_t)N_TOK * D * sizeof(float), stream);
        hipMemsetAsync(scotab, 0, (size_t)PADCAP * sizeof(float), stream);
        hipMemsetAsync(tokentab, 0, (size_t)PADCAP * sizeof(int), stream);
    }
    hipLaunchKernelGGL(topk15_kernel, dim3((N_TOK / 64) * 4), dim3(256), 0, stream,
                       xh, xl, cbf, c2g, pkbuf);
    hipLaunchKernelGGL(topmerge_kernel, dim3(N_TOK / 256), dim3(256), 0, stream,
                       pkbuf, scores, sidx, hist);
    hipLaunchKernelGGL(scatter5_kernel, dim3(256), dim3(256), 0, stream,
                       hist, sidx, scores, cursor, tokentab, scotab, meta);
    if (fast) {
        hipLaunchKernelGGL(mix17_kernel, dim3(PADCAP / 128), dim3(256), 0, stream,
                           xh, wbt, Ov, tokentab, scotab, meta, partial);
        hipLaunchKernelGGL(redu2_kernel, dim3(N_TOK * 8 / 256), dim3(256), 0, stream,
                           partial, out);
    } else {
        hipLaunchKernelGGL(mix14_kernel, dim3(PADCAP / 128), dim3(256), 0, stream,
                           x, Wv, Ov, tokentab, scotab, meta, out);
    }
}